// Round 10
// baseline (342.901 us; speedup 1.0000x reference)
//
#include <hip/hip_runtime.h>
#include <hip/hip_bf16.h>

#define D   128
#define DM  256
#define DI  512
#define HH  512
#define KNN 10
#define NN  64
#define BQ  4096
#define BS  128
#define BM2 (BQ + BS)        // 4224 batched se rows
#define G2  1024             // live LSTM gate rows (4 gates x 256 live units)
#define GK  256              // LSTM GEMM K
#define NSYM 200000
#define NEB (BQ * 2 + BS * 2)   // 8448 ne blocks
#define BKT 64
#define LDP (BKT + 8)

__device__ __forceinline__ float sigmoidf_(float x) {
    return 1.f / (1.f + __expf(-x));
}
__device__ __forceinline__ float tanh_fast(float x) {
    x = fminf(fmaxf(x, -20.f), 20.f);
    float e = __expf(2.f * x);
    return (e - 1.f) / (e + 1.f);
}
__device__ __forceinline__ ushort f2bf(float x) {
    union { float f; unsigned u; } v; v.f = x;
    unsigned r = (v.u + 0x7fffu + ((v.u >> 16) & 1u)) >> 16;  // RNE
    return (ushort)r;
}

typedef __bf16  bf16x8  __attribute__((ext_vector_type(8)));
typedef float   floatx4 __attribute__((ext_vector_type(4)));

// ---------------- ne + prep merged (independent work, one dispatch) ----------------
// blocks [0, 8448): neighbor encoder.  blocks [8448, 8448+1536): weight conversion.
// LESSON (r3/r4): scattered 256B-granule reads run at ~1.15 TB/s vs ~2.7-3.2 TB/s
// for 512B-granule — fp32 rows are FASTER despite 2x bytes. Norms in-pass.
// LESSON (r7/r8): per-dispatch gap ~2.5us; fuse only independent or row-local work.
__global__ __launch_bounds__(256) void ne_prep_kernel(
    const int* __restrict__ q_l, const int* __restrict__ q_r,
    const int* __restrict__ q_ids,
    const int* __restrict__ s_l, const int* __restrict__ s_r,
    const int* __restrict__ s_ids,
    const float* __restrict__ emb,
    float* __restrict__ catm_out,
    const float* __restrict__ W_ih, const float* __restrict__ W_hh,
    const float* __restrict__ b_ih, const float* __restrict__ b_hh,
    const float* __restrict__ se_w1, const float* __restrict__ se_w2,
    ushort* __restrict__ wih_bf, ushort* __restrict__ whh_bf,
    float* __restrict__ bsumP, ushort* __restrict__ w1_bf,
    ushort* __restrict__ w2_bf)
{
    int bid = blockIdx.x;
    int tid = threadIdx.x;

    if (bid >= NEB) {
        // ---------------- prep section ----------------
        int pb = bid - NEB;
        if (pb < G2) {
            // permuted row n: bn=n>>7, r=n&127, half=(r>>6)&1, j=(r>>4)&3, l=r&15
            //   unit u = bn*32 + half*16 + l (0..255), old gate row = j*512 + u
            int n = pb;
            int bn = n >> 7, r = n & 127;
            int half = (r >> 6) & 1, j = (r >> 4) & 3, l = r & 15;
            int u = bn * 32 + half * 16 + l;
            int oldrow = j * 512 + u;
            wih_bf[n * 256 + tid] = f2bf(W_ih[(size_t)oldrow * DM + tid]);
            whh_bf[n * 256 + tid] = f2bf(W_hh[(size_t)oldrow * HH + tid]);
            if (tid == 0) bsumP[n] = b_ih[oldrow] + b_hh[oldrow];
        } else {
            int idx = (pb - G2) * 256 + tid;   // 0..131071
            w1_bf[idx] = f2bf(se_w1[idx]);
            w2_bf[idx] = f2bf(se_w2[idx]);
        }
        return;
    }

    // ---------------- neighbor encoder section ----------------
    const int *conn_l, *conn_r, *ids;
    int row;
    if (bid < BQ * 2) { conn_l = q_l; conn_r = q_r; ids = q_ids; row = bid >> 1; }
    else { conn_l = s_l; conn_r = s_r; ids = s_ids; row = (bid - BQ * 2) >> 1; }
    int side = bid & 1;
    const int* conn = (side ? conn_r : conn_l) + (size_t)row * NN * 2;
    int cid = ids[row * 2 + side];

    __shared__ int   connb[NN * 2];
    __shared__ float sim[NN];
    __shared__ int   selr[KNN], sele[KNN];

    int wave = tid >> 6, lane = tid & 63;
    int grp = lane >> 4, l16 = lane & 15;

    if (tid < NN * 2) connb[tid] = conn[tid];
    const float* cp = &emb[(size_t)cid * D + l16 * 8];
    float4 c4a = *(const float4*)cp;
    float4 c4b = *(const float4*)(cp + 4);
    float cs = c4a.x * c4a.x + c4a.y * c4a.y + c4a.z * c4a.z + c4a.w * c4a.w
             + c4b.x * c4b.x + c4b.y * c4b.y + c4b.z * c4b.z + c4b.w * c4b.w;
    #pragma unroll
    for (int off = 8; off; off >>= 1) cs += __shfl_xor(cs, off);
    float cnorm = fmaxf(sqrtf(cs), 1e-8f);
    __syncthreads();

    float4 ea[4], eb[4];
    #pragma unroll
    for (int b = 0; b < 4; b++) {
        int j = wave * 16 + b * 4 + grp;
        int eid = connb[j * 2 + 1];
        const float* ep = &emb[(size_t)eid * D + l16 * 8];
        ea[b] = *(const float4*)ep;
        eb[b] = *(const float4*)(ep + 4);
    }
    #pragma unroll
    for (int b = 0; b < 4; b++) {
        int j = wave * 16 + b * 4 + grp;
        float dot = c4a.x * ea[b].x + c4a.y * ea[b].y + c4a.z * ea[b].z + c4a.w * ea[b].w
                  + c4b.x * eb[b].x + c4b.y * eb[b].y + c4b.z * eb[b].z + c4b.w * eb[b].w;
        float ee  = ea[b].x * ea[b].x + ea[b].y * ea[b].y + ea[b].z * ea[b].z + ea[b].w * ea[b].w
                  + eb[b].x * eb[b].x + eb[b].y * eb[b].y + eb[b].z * eb[b].z + eb[b].w * eb[b].w;
        #pragma unroll
        for (int off = 8; off; off >>= 1) {
            dot += __shfl_xor(dot, off);
            ee  += __shfl_xor(ee, off);
        }
        if (l16 == 0) sim[j] = dot / (cnorm * fmaxf(sqrtf(ee), 1e-8f));
    }
    __syncthreads();

    if (wave == 0) {
        float s = sim[lane];
        int id = lane;
        for (int k = 0; k < KNN; k++) {
            float bs = s; int bi = id;
            #pragma unroll
            for (int off = 32; off; off >>= 1) {
                float os = __shfl_xor(bs, off);
                int   oi = __shfl_xor(bi, off);
                if (os > bs || (os == bs && oi < bi)) { bs = os; bi = oi; }
            }
            if (lane == 0) { selr[k] = connb[bi * 2]; sele[k] = connb[bi * 2 + 1]; }
            if (id == bi) s = -__builtin_inff();
        }
    }
    __syncthreads();

    float acc = 0.f;
    if (tid < D) {
        #pragma unroll
        for (int k = 0; k < KNN; k++) acc += emb[(size_t)selr[k] * D + tid];
    } else {
        int d = tid - D;
        #pragma unroll
        for (int k = 0; k < KNN; k++) acc += emb[(size_t)sele[k] * D + d];
    }
    catm_out[(size_t)bid * DM + tid] = acc * (1.f / KNN);
}

// ---------------- fused mid: gcn -> se1 -> se2 -> LayerNorm (all row-local) ----------------
// grid = 264 blocks x 16 se-rows (32 catm rows). All intermediates (x, t1, ys)
// live in LDS; w1/w2 B-fragments stream from L2 (0.5 MB, shared across blocks).
// Per-element math is a verbatim replica of the old gcn/se1/se2/ln kernels:
// MFMA K ascending in 32-chunks (tile shape doesn't change per-element sums),
// gcn fp32 chain and ln reduce copied exactly -> bitwise-identical results.
// LDS 64 KB -> 2 blocks/CU.
__global__ __launch_bounds__(256) void mid_kernel(
    const float* __restrict__ catm,
    const float* __restrict__ gcn_W, const float* __restrict__ gcn_wb,
    const float* __restrict__ gcn_b,
    const ushort* __restrict__ w1, const float* __restrict__ b1,
    const ushort* __restrict__ w2, const float* __restrict__ b2,
    const float* __restrict__ ln_g, const float* __restrict__ ln_b,
    float* __restrict__ outf, ushort* __restrict__ outbf)
{
    __shared__ __align__(16) char smem[65536];
    float*  catm_s = (float*)smem;              // [32][256] fp32 (phase 1)
    float*  xs     = (float*)smem;              // [32][128] fp32 (reuses catm_s)
    ushort* xb_s   = (ushort*)(smem + 16384);   // [32][128] bf16, chunk^((r>>1)&15) swizzle
    float*  pp     = (float*)(smem + 32768);    // [32][256] fp32 (phase 1)
    ushort* t1s    = (ushort*)(smem + 32768);   // [16][512] bf16, chunk^(m&15) swizzle (reuses pp)
    float*  ys_s   = (float*)(smem + 49152);    // [16][256] fp32

    int tid = threadIdx.x;
    int bm = blockIdx.x;
    int wave = tid >> 6, lane = tid & 63;
    int quad = lane >> 4, l16 = lane & 15;

    // ---- stage 32 catm rows (32 KB) ----
    #pragma unroll
    for (int t = 0; t < 8; t++) {
        int ch = t * 256 + tid;
        int r = ch >> 6, c4 = ch & 63;
        *(float4*)&catm_s[r * 256 + c4 * 4] =
            *(const float4*)&catm[(size_t)(bm * 32 + r) * DM + c4 * 4];
    }
    __syncthreads();

    // ---- gcn partials (verbatim math, 32 rows) ----
    {
        int d = tid & 127, half = tid >> 7;
        float a[32];
        #pragma unroll
        for (int r = 0; r < 32; r++) a[r] = 0.f;
        const float4* W4 = (const float4*)(gcn_W + (size_t)d * DM + half * D);
        for (int f4 = 0; f4 < D / 4; ++f4) {
            float4 w = W4[f4];
            #pragma unroll
            for (int r = 0; r < 32; r++) {
                const float* c = &catm_s[r * 256 + half * D + f4 * 4];
                a[r] += w.x * c[0] + w.y * c[1] + w.z * c[2] + w.w * c[3];
            }
        }
        #pragma unroll
        for (int r = 0; r < 32; r++) pp[r * 256 + tid] = a[r];
    }
    __syncthreads();

    // ---- combine + tanh; write xs (fp32) + xb (bf16 swizzled) over catm_s ----
    if (tid < D) {
        #pragma unroll
        for (int r = 0; r < 32; r++) {
            float h = pp[r * 256 + tid] + pp[r * 256 + tid + D] + gcn_wb[tid] + gcn_b[tid];
            float th = tanh_fast(h);
            xs[r * 128 + tid] = th;
            int c16 = tid >> 3, e = tid & 7;
            xb_s[r * 128 + (((c16 ^ ((r >> 1) & 15)) << 3) + e)] = f2bf(th);
        }
    }
    __syncthreads();

    // ---- se1: t1 = relu(x @ w1^T + b1) -> t1s (over pp) ----
    {
        floatx4 acc[8];
        #pragma unroll
        for (int j = 0; j < 8; j++) acc[j] = (floatx4){0.f, 0.f, 0.f, 0.f};
        #pragma unroll
        for (int kk = 0; kk < DM; kk += 32) {
            int c = (kk >> 3) + quad;              // chunk in [0,32) over k=[0,256)
            int r = 2 * l16 + (c >= 16);           // catm-row; (r>>1)&15 == l16
            int c15 = c & 15;
            bf16x8 af = *(const bf16x8*)&xb_s[r * 128 + ((c15 ^ l16) << 3)];
            #pragma unroll
            for (int j = 0; j < 8; j++) {
                int cr = wave * 128 + j * 16 + l16;
                bf16x8 bv = *(const bf16x8*)&w1[(size_t)cr * DM + kk + quad * 8];
                acc[j] = __builtin_amdgcn_mfma_f32_16x16x32_bf16(af, bv, acc[j], 0, 0, 0);
            }
        }
        #pragma unroll
        for (int j = 0; j < 8; j++) {
            int col = wave * 128 + j * 16 + l16;
            float bb = b1[col];
            #pragma unroll
            for (int rr = 0; rr < 4; rr++) {
                int m = quad * 4 + rr;
                float v = fmaxf(acc[j][rr] + bb, 0.f);
                int cc = col >> 3, e = col & 7;
                t1s[m * 512 + (((cc ^ (m & 15)) << 3) + e)] = f2bf(v);
            }
        }
    }
    __syncthreads();

    // ---- se2: ys = t1 @ w2^T + b2 + x -> ys_s ----
    {
        floatx4 acc[4];
        #pragma unroll
        for (int j = 0; j < 4; j++) acc[j] = (floatx4){0.f, 0.f, 0.f, 0.f};
        #pragma unroll
        for (int kk = 0; kk < DI; kk += 32) {
            int c = (kk >> 3) + quad;              // chunk in [0,64)
            bf16x8 af = *(const bf16x8*)&t1s[l16 * 512 + ((c ^ l16) << 3)];
            #pragma unroll
            for (int j = 0; j < 4; j++) {
                int cr = wave * 64 + j * 16 + l16;
                bf16x8 bv = *(const bf16x8*)&w2[(size_t)cr * DI + kk + quad * 8];
                acc[j] = __builtin_amdgcn_mfma_f32_16x16x32_bf16(af, bv, acc[j], 0, 0, 0);
            }
        }
        #pragma unroll
        for (int j = 0; j < 4; j++) {
            int col = wave * 64 + j * 16 + l16;
            float bb = b2[col];
            #pragma unroll
            for (int rr = 0; rr < 4; rr++) {
                int m = quad * 4 + rr;
                ys_s[m * 256 + col] = acc[j][rr] + bb + xs[m * 256 + col];
            }
        }
    }
    __syncthreads();

    // ---- LayerNorm (verbatim per-row math), write ln_f + ln_bf to global ----
    #pragma unroll
    for (int rr2 = 0; rr2 < 4; rr2++) {
        int m = wave * 4 + rr2;
        int rg = bm * 16 + m;
        float vals[4];
        float s = 0.f;
        #pragma unroll
        for (int e = 0; e < 4; e++) {
            vals[e] = ys_s[m * 256 + e * 64 + lane];
            s += vals[e];
        }
        #pragma unroll
        for (int off = 32; off; off >>= 1) s += __shfl_xor(s, off);
        float mu = s * (1.f / DM);
        float v = 0.f;
        #pragma unroll
        for (int e = 0; e < 4; e++) { float dd = vals[e] - mu; v += dd * dd; }
        #pragma unroll
        for (int off = 32; off; off >>= 1) v += __shfl_xor(v, off);
        float rstd = rsqrtf(v * (1.f / DM) + 1e-5f);
        #pragma unroll
        for (int e = 0; e < 4; e++) {
            int dd = e * 64 + lane;
            float ov = (vals[e] - mu) * rstd * ln_g[dd] + ln_b[dd];
            outf[(size_t)rg * DM + dd] = ov;
            outbf[(size_t)rg * DM + dd] = f2bf(ov);
        }
    }
}

// ---------------- 64x128-tile bf16 MFMA GEMM (2 blocks/CU for latency overlap) ----------------
#define GEMM64_VARS()                                                         \
    __shared__ __align__(16) ushort As[64][LDP];                              \
    __shared__ __align__(16) ushort Bs[128][LDP];                             \
    int tid = threadIdx.x;                                                    \
    int wave = tid >> 6, lane = tid & 63;                                     \
    int quad = lane >> 4, l16 = lane & 15;                                    \
    int wm = (wave >> 1) * 32, wn = (wave & 1) * 64;

#define GEMM64_CORE(AP, BP, KDIM)                                             \
    floatx4 acc[2][4];                                                        \
    _Pragma("unroll")                                                         \
    for (int i = 0; i < 2; i++)                                               \
        _Pragma("unroll")                                                     \
        for (int j = 0; j < 4; j++) acc[i][j] = (floatx4){0.f, 0.f, 0.f, 0.f};\
    for (int k0 = 0; k0 < (KDIM); k0 += BKT) {                                \
        __syncthreads();                                                      \
        _Pragma("unroll")                                                     \
        for (int t = 0; t < 2; t++) {                                         \
            int ch = t * 256 + tid;                                           \
            int r = ch >> 3, c8 = (ch & 7) * 8;                               \
            *(uint4*)&As[r][c8] = *(const uint4*)&(AP)[(size_t)(bm * 64 + r) * (KDIM) + k0 + c8]; \
        }                                                                     \
        _Pragma("unroll")                                                     \
        for (int t = 0; t < 4; t++) {                                         \
            int ch = t * 256 + tid;                                           \
            int r = ch >> 3, c8 = (ch & 7) * 8;                               \
            *(uint4*)&Bs[r][c8] = *(const uint4*)&(BP)[(size_t)(bn * 128 + r) * (KDIM) + k0 + c8]; \
        }                                                                     \
        __syncthreads();                                                      \
        _Pragma("unroll")                                                     \
        for (int kk = 0; kk < BKT; kk += 32) {                                \
            bf16x8 af[2], bv[4];                                              \
            _Pragma("unroll")                                                 \
            for (int i = 0; i < 2; i++)                                       \
                af[i] = *(const bf16x8*)&As[wm + i * 16 + l16][kk + quad * 8];\
            _Pragma("unroll")                                                 \
            for (int j = 0; j < 4; j++)                                       \
                bv[j] = *(const bf16x8*)&Bs[wn + j * 16 + l16][kk + quad * 8];\
            _Pragma("unroll")                                                 \
            for (int i = 0; i < 2; i++)                                       \
                _Pragma("unroll")                                             \
                for (int j = 0; j < 4; j++)                                   \
                    acc[i][j] = __builtin_amdgcn_mfma_f32_16x16x32_bf16(      \
                        af[i], bv[j], acc[i][j], 0, 0, 0);                    \
        }                                                                     \
    }

// ---------------- LSTM GEMM step 1 + fused sgw (blocks 512..515) ----------------
__global__ __launch_bounds__(256) void lstm_gemm0_sgw_kernel(
    const ushort* __restrict__ A, const ushort* __restrict__ B,
    const float* __restrict__ bsumP, const float* __restrict__ lnf,
    float* __restrict__ P0f, float* __restrict__ Cf, ushort* __restrict__ h_out,
    const float* __restrict__ W_hh, const float* __restrict__ b_ih,
    const float* __restrict__ b_hh, float* __restrict__ sg,
    float* __restrict__ gaddP)
{
    if (blockIdx.x >= 512) {
        // ---- sgw section ----
        __shared__ float s[DM];
        int tid = threadIdx.x;
        int sb = blockIdx.x - 512;
        float a = 0.f;
        for (int r = 0; r < BS; r++) a += lnf[(size_t)(BQ + r) * DM + tid];
        a *= (1.f / BS);
        s[tid] = a;
        if (sb == 0) sg[tid] = a;
        __syncthreads();

        int idx = sb * 256 + tid;              // 0..1023
        int g = idx >> 8, u = idx & 255;       // gate, live unit
        int oldrow = g * 512 + u;
        const float4* w4 = (const float4*)(W_hh + (size_t)oldrow * HH + DM);
        float acc = 0.f;
        for (int f4 = 0; f4 < DM / 4; ++f4) {
            float4 w = w4[f4];
            acc += w.x * s[f4 * 4] + w.y * s[f4 * 4 + 1] + w.z * s[f4 * 4 + 2] + w.w * s[f4 * 4 + 3];
        }
        float bs = b_ih[oldrow] + b_hh[oldrow];
        int n = (u >> 5) * 128 + ((u >> 4) & 1) * 64 + g * 16 + (u & 15);
        gaddP[n] = bs + acc;
        return;
    }

    // ---- gemm0 section ----
    GEMM64_VARS();
    int bm = blockIdx.x >> 3, bn = blockIdx.x & 7;
    GEMM64_CORE(A, B, GK);
    int u = bn * 32 + (wn ? 16 : 0) + l16;
    size_t tile = (size_t)bm * 8 + bn;
    float b4[4];
    #pragma unroll
    for (int j = 0; j < 4; j++) b4[j] = bsumP[bn * 128 + wn + j * 16 + l16];
    #pragma unroll
    for (int i = 0; i < 2; i++) {
        int row = bm * 64 + wm + i * 16 + quad * 4;
        #pragma unroll
        for (int j = 0; j < 4; j++)
            *(floatx4*)&P0f[((tile * 8 + i * 4 + j) * 256 + tid) * 4] = acc[i][j];
        floatx4 cv4;
        #pragma unroll
        for (int rr = 0; rr < 4; rr++) {
            float iv = acc[i][0][rr] + b4[0];
            float gv = acc[i][2][rr] + b4[2];
            float ov = acc[i][3][rr] + b4[3];
            float cv = sigmoidf_(iv) * tanh_fast(gv);
            cv4[rr] = cv;
            float h = lnf[(size_t)(row + rr) * DM + u] + sigmoidf_(ov) * tanh_fast(cv);
            h_out[(size_t)(row + rr) * DM + u] = f2bf(h);
        }
        *(floatx4*)&Cf[((tile * 2 + i) * 256 + tid) * 4] = cv4;
    }
}

// ---------------- LSTM GEMM steps 2..4 (fused ew): grid (64, 8) ----------------
__global__ __launch_bounds__(256) void lstm_step_kernel(
    const ushort* __restrict__ A, const ushort* __restrict__ B,
    const float* __restrict__ P0f, const float* __restrict__ gaddP,
    const float* __restrict__ lnf, float* __restrict__ Cf,
    ushort* __restrict__ h_out, float* __restrict__ hf_out, int last)
{
    GEMM64_VARS();
    int bm = blockIdx.x, bn = blockIdx.y;
    GEMM64_CORE(A, B, GK);
    int u = bn * 32 + (wn ? 16 : 0) + l16;
    size_t tile = (size_t)bm * 8 + bn;
    float g4[4];
    #pragma unroll
    for (int j = 0; j < 4; j++) g4[j] = gaddP[bn * 128 + wn + j * 16 + l16];
    #pragma unroll
    for (int i = 0; i < 2; i++) {
        int row = bm * 64 + wm + i * 16 + quad * 4;
        floatx4 p0[4];
        #pragma unroll
        for (int j = 0; j < 4; j++)
            p0[j] = *(const floatx4*)&P0f[((tile * 8 + i * 4 + j) * 256 + tid) * 4];
        floatx4 cprev = *(const floatx4*)&Cf[((tile * 2 + i) * 256 + tid) * 4];
        floatx4 cnew;
        #pragma unroll
        for (int rr = 0; rr < 4; rr++) {
            float iv = acc[i][0][rr] + p0[0][rr] + g4[0];
            float fv = acc[i][1][rr] + p0[1][rr] + g4[1];
            float gv = acc[i][2][rr] + p0[2][rr] + g4[2];
            float ov = acc[i][3][rr] + p0[3][rr] + g4[3];
            float cv = sigmoidf_(fv) * cprev[rr] + sigmoidf_(iv) * tanh_fast(gv);
            cnew[rr] = cv;
            float h = lnf[(size_t)(row + rr) * DM + u] + sigmoidf_(ov) * tanh_fast(cv);
            if (last) hf_out[(size_t)(row + rr) * DM + u] = h;
            else      h_out[(size_t)(row + rr) * DM + u] = f2bf(h);
        }
        *(floatx4*)&Cf[((tile * 2 + i) * 256 + tid) * 4] = cnew;
    }
}

// ---------------- final cosine ----------------
__global__ __launch_bounds__(256) void final_kernel(
    const float* __restrict__ h_ws, const float* __restrict__ sg,
    float* __restrict__ outp)
{
    __shared__ float sgs[DM];
    int tid = threadIdx.x;
    sgs[tid] = sg[tid];
    __syncthreads();
    int wave = tid >> 6, lane = tid & 63;
    float sn = 0.f;
    #pragma unroll
    for (int e = 0; e < 4; e++) { float v = sgs[e * 64 + lane]; sn += v * v; }
    #pragma unroll
    for (int off = 32; off; off >>= 1) sn += __shfl_xor(sn, off);
    float sgnorm = fmaxf(sqrtf(sn), 1e-12f);

    int row = blockIdx.x * 4 + wave;
    const float* h = h_ws + (size_t)row * DM;
    float dot = 0.f, hn = 0.f;
    #pragma unroll
    for (int e = 0; e < 4; e++) {
        float hv = h[e * 64 + lane];
        dot += hv * sgs[e * 64 + lane];
        hn += hv * hv;
    }
    #pragma unroll
    for (int off = 32; off; off >>= 1) { dot += __shfl_xor(dot, off); hn += __shfl_xor(hn, off); }
    if (lane == 0) outp[row] = dot / (fmaxf(sqrtf(hn), 1e-12f) * sgnorm);
}

extern "C" void kernel_launch(void* const* d_in, const int* in_sizes, int n_in,
                              void* d_out, int out_size, void* d_ws, size_t ws_size,
                              hipStream_t stream)
{
    const int* query    = (const int*)d_in[0];
    const int* support  = (const int*)d_in[1];
    const int* q_l_conn = (const int*)d_in[2];
    const int* q_r_conn = (const int*)d_in[4];
    const int* s_l_conn = (const int*)d_in[6];
    const int* s_r_conn = (const int*)d_in[8];
    const float* emb    = (const float*)d_in[10];
    const float* gcn_W  = (const float*)d_in[11];
    const float* gcn_wb = (const float*)d_in[12];
    const float* gcn_b  = (const float*)d_in[13];
    const float* se_w1  = (const float*)d_in[14];
    const float* se_b1  = (const float*)d_in[15];
    const float* se_w2  = (const float*)d_in[16];
    const float* se_b2  = (const float*)d_in[17];
    const float* ln_g   = (const float*)d_in[18];
    const float* ln_b   = (const float*)d_in[19];
    const float* W_ih   = (const float*)d_in[20];
    const float* W_hh   = (const float*)d_in[21];
    const float* b_ih   = (const float*)d_in[22];
    const float* b_hh   = (const float*)d_in[23];
    float* out = (float*)d_out;

    char* wsb = (char*)d_ws;
    float*  ln_f   = (float*)wsb;  wsb += (size_t)BM2 * DM * 4;   // post-LN fp32
    ushort* ln_bf  = (ushort*)wsb; wsb += (size_t)BM2 * DM * 2;   // post-LN bf16
    float*  sg     = (float*)wsb;  wsb += DM * 4;
    float*  bsumP  = (float*)wsb;  wsb += G2 * 4;
    float*  gaddP  = (float*)wsb;  wsb += G2 * 4;
    ushort* wih_bf = (ushort*)wsb; wsb += (size_t)G2 * DM * 2;
    ushort* whh_bf = (ushort*)wsb; wsb += (size_t)G2 * DM * 2;
    ushort* w1_bf  = (ushort*)wsb; wsb += (size_t)DI * DM * 2;
    ushort* w2_bf  = (ushort*)wsb; wsb += (size_t)DM * DI * 2;
    float*  P0f    = (float*)wsb;  wsb += (size_t)BQ * G2 * 4;    // frag tid-fast
    float*  Cf     = (float*)wsb;  wsb += (size_t)BQ * DM * 4;    // live c only
    ushort* h_bfA  = (ushort*)wsb; wsb += (size_t)BQ * DM * 2;
    ushort* h_bfB  = (ushort*)wsb; wsb += (size_t)BQ * DM * 2;
    float*  h_f    = (float*)wsb;  wsb += (size_t)BQ * DM * 4;

    // catm [8448][256] (8.65 MB) aliases P0f (16 MB; dead until lstm_gemm0)
    float* catm = P0f;

    ne_prep_kernel<<<NEB + G2 + 512, 256, 0, stream>>>(
        q_l_conn, q_r_conn, query, s_l_conn, s_r_conn, support,
        emb, catm,
        W_ih, W_hh, b_ih, b_hh, se_w1, se_w2,
        wih_bf, whh_bf, bsumP, w1_bf, w2_bf);

    mid_kernel<<<BM2 / 16, 256, 0, stream>>>(
        catm, gcn_W, gcn_wb, gcn_b,
        w1_bf, se_b1, w2_bf, se_b2, ln_g, ln_b,
        ln_f, ln_bf);

    lstm_gemm0_sgw_kernel<<<516, 256, 0, stream>>>(
        ln_bf, wih_bf, bsumP, ln_f, P0f, Cf, h_bfA,
        W_hh, b_ih, b_hh, sg, gaddP);

    dim3 ggrid(BQ / 64, G2 / 128);    // (64, 8)
    lstm_step_kernel<<<ggrid, 256, 0, stream>>>(h_bfA, whh_bf, P0f, gaddP, ln_f,
                                                Cf, h_bfB, h_f, 0);
    lstm_step_kernel<<<ggrid, 256, 0, stream>>>(h_bfB, whh_bf, P0f, gaddP, ln_f,
                                                Cf, h_bfA, h_f, 0);
    lstm_step_kernel<<<ggrid, 256, 0, stream>>>(h_bfA, whh_bf, P0f, gaddP, ln_f,
                                                Cf, h_bfB, h_f, 1);
    final_kernel<<<BQ / 4, 256, 0, stream>>>(h_f, sg, out);
}

// Round 11
// 337.668 us; speedup vs baseline: 1.0155x; 1.0155x over previous
//
#include <hip/hip_runtime.h>
#include <hip/hip_bf16.h>

#define D   128
#define DM  256
#define DI  512
#define HH  512
#define KNN 10
#define NN  64
#define BQ  4096
#define BS  128
#define BM2 (BQ + BS)        // 4224 batched se rows
#define G2  1024             // live LSTM gate rows (4 gates x 256 live units)
#define GK  256              // LSTM GEMM K (per weight half)
#define NSYM 200000
#define NEB (BQ * 2 + BS * 2)   // 8448 ne blocks
#define BKT 64
#define LDP (BKT + 8)

__device__ __forceinline__ float sigmoidf_(float x) {
    return 1.f / (1.f + __expf(-x));
}
__device__ __forceinline__ float tanh_fast(float x) {
    x = fminf(fmaxf(x, -20.f), 20.f);
    float e = __expf(2.f * x);
    return (e - 1.f) / (e + 1.f);
}
__device__ __forceinline__ ushort f2bf(float x) {
    union { float f; unsigned u; } v; v.f = x;
    unsigned r = (v.u + 0x7fffu + ((v.u >> 16) & 1u)) >> 16;  // RNE
    return (ushort)r;
}

typedef __bf16  bf16x8  __attribute__((ext_vector_type(8)));
typedef float   floatx4 __attribute__((ext_vector_type(4)));

// ---------------- ne + prep merged (independent work, one dispatch) ----------------
// blocks [0, 8448): neighbor encoder.  blocks [8448, 8448+1536): weight conversion.
// LESSON (r3/r4): scattered 256B-granule reads run at ~1.15 TB/s vs ~2.7-3.2 TB/s
// for 512B-granule — fp32 rows are FASTER despite 2x bytes. Norms in-pass.
// LESSON (r7/r8/r10): per-dispatch gap ~2.5us; fuse only independent work —
// row-local chains fused into one kernel LOST (mid_kernel, r10: +15us vs parts).
__global__ __launch_bounds__(256) void ne_prep_kernel(
    const int* __restrict__ q_l, const int* __restrict__ q_r,
    const int* __restrict__ q_ids,
    const int* __restrict__ s_l, const int* __restrict__ s_r,
    const int* __restrict__ s_ids,
    const float* __restrict__ emb,
    float* __restrict__ catm_out,
    const float* __restrict__ W_ih, const float* __restrict__ W_hh,
    const float* __restrict__ b_ih, const float* __restrict__ b_hh,
    const float* __restrict__ se_w1, const float* __restrict__ se_w2,
    ushort* __restrict__ wcomb,
    float* __restrict__ bsumP, ushort* __restrict__ w1_bf,
    ushort* __restrict__ w2_bf)
{
    int bid = blockIdx.x;
    int tid = threadIdx.x;

    if (bid >= NEB) {
        // ---------------- prep section ----------------
        int pb = bid - NEB;
        if (pb < G2) {
            // permuted row n: bn=n>>7, r=n&127, half=(r>>6)&1, j=(r>>4)&3, l=r&15
            //   unit u = bn*32 + half*16 + l (0..255), old gate row = j*512 + u
            // wcomb row n: cols [0,256) = wih_perm, cols [256,512) = whh_perm
            int n = pb;
            int bn = n >> 7, r = n & 127;
            int half = (r >> 6) & 1, j = (r >> 4) & 3, l = r & 15;
            int u = bn * 32 + half * 16 + l;
            int oldrow = j * 512 + u;
            wcomb[(size_t)n * 512 + tid]       = f2bf(W_ih[(size_t)oldrow * DM + tid]);
            wcomb[(size_t)n * 512 + 256 + tid] = f2bf(W_hh[(size_t)oldrow * HH + tid]);
            if (tid == 0) bsumP[n] = b_ih[oldrow] + b_hh[oldrow];
        } else {
            int idx = (pb - G2) * 256 + tid;   // 0..131071
            w1_bf[idx] = f2bf(se_w1[idx]);
            w2_bf[idx] = f2bf(se_w2[idx]);
        }
        return;
    }

    // ---------------- neighbor encoder section ----------------
    const int *conn_l, *conn_r, *ids;
    int row;
    if (bid < BQ * 2) { conn_l = q_l; conn_r = q_r; ids = q_ids; row = bid >> 1; }
    else { conn_l = s_l; conn_r = s_r; ids = s_ids; row = (bid - BQ * 2) >> 1; }
    int side = bid & 1;
    const int* conn = (side ? conn_r : conn_l) + (size_t)row * NN * 2;
    int cid = ids[row * 2 + side];

    __shared__ int   connb[NN * 2];
    __shared__ float sim[NN];
    __shared__ int   selr[KNN], sele[KNN];

    int wave = tid >> 6, lane = tid & 63;
    int grp = lane >> 4, l16 = lane & 15;

    if (tid < NN * 2) connb[tid] = conn[tid];
    const float* cp = &emb[(size_t)cid * D + l16 * 8];
    float4 c4a = *(const float4*)cp;
    float4 c4b = *(const float4*)(cp + 4);
    float cs = c4a.x * c4a.x + c4a.y * c4a.y + c4a.z * c4a.z + c4a.w * c4a.w
             + c4b.x * c4b.x + c4b.y * c4b.y + c4b.z * c4b.z + c4b.w * c4b.w;
    #pragma unroll
    for (int off = 8; off; off >>= 1) cs += __shfl_xor(cs, off);
    float cnorm = fmaxf(sqrtf(cs), 1e-8f);
    __syncthreads();

    float4 ea[4], eb[4];
    #pragma unroll
    for (int b = 0; b < 4; b++) {
        int j = wave * 16 + b * 4 + grp;
        int eid = connb[j * 2 + 1];
        const float* ep = &emb[(size_t)eid * D + l16 * 8];
        ea[b] = *(const float4*)ep;
        eb[b] = *(const float4*)(ep + 4);
    }
    #pragma unroll
    for (int b = 0; b < 4; b++) {
        int j = wave * 16 + b * 4 + grp;
        float dot = c4a.x * ea[b].x + c4a.y * ea[b].y + c4a.z * ea[b].z + c4a.w * ea[b].w
                  + c4b.x * eb[b].x + c4b.y * eb[b].y + c4b.z * eb[b].z + c4b.w * eb[b].w;
        float ee  = ea[b].x * ea[b].x + ea[b].y * ea[b].y + ea[b].z * ea[b].z + ea[b].w * ea[b].w
                  + eb[b].x * eb[b].x + eb[b].y * eb[b].y + eb[b].z * eb[b].z + eb[b].w * eb[b].w;
        #pragma unroll
        for (int off = 8; off; off >>= 1) {
            dot += __shfl_xor(dot, off);
            ee  += __shfl_xor(ee, off);
        }
        if (l16 == 0) sim[j] = dot / (cnorm * fmaxf(sqrtf(ee), 1e-8f));
    }
    __syncthreads();

    if (wave == 0) {
        float s = sim[lane];
        int id = lane;
        for (int k = 0; k < KNN; k++) {
            float bs = s; int bi = id;
            #pragma unroll
            for (int off = 32; off; off >>= 1) {
                float os = __shfl_xor(bs, off);
                int   oi = __shfl_xor(bi, off);
                if (os > bs || (os == bs && oi < bi)) { bs = os; bi = oi; }
            }
            if (lane == 0) { selr[k] = connb[bi * 2]; sele[k] = connb[bi * 2 + 1]; }
            if (id == bi) s = -__builtin_inff();
        }
    }
    __syncthreads();

    float acc = 0.f;
    if (tid < D) {
        #pragma unroll
        for (int k = 0; k < KNN; k++) acc += emb[(size_t)selr[k] * D + tid];
    } else {
        int d = tid - D;
        #pragma unroll
        for (int k = 0; k < KNN; k++) acc += emb[(size_t)sele[k] * D + d];
    }
    catm_out[(size_t)bid * DM + tid] = acc * (1.f / KNN);
}

// ---------------- batched GCN transform ----------------
#define GR 16
__global__ __launch_bounds__(256) void gcn_kernel(
    const float* __restrict__ catm, const float* __restrict__ gcn_W,
    const float* __restrict__ gcn_wb, const float* __restrict__ gcn_b,
    float* __restrict__ out, ushort* __restrict__ out_bf)
{
    __shared__ float cs[GR][DM];
    __shared__ float pp[GR][DM];
    int tid = threadIdx.x;
    int m0 = blockIdx.x * GR;
    #pragma unroll
    for (int t = 0; t < 4; t++) {
        int chunk = tid + 256 * t;
        int r = chunk >> 6, c4 = chunk & 63;
        *(float4*)&cs[r][c4 * 4] = *(const float4*)&catm[(size_t)(m0 + r) * DM + c4 * 4];
    }
    __syncthreads();

    int d = tid & 127, half = tid >> 7;
    float a[GR];
    #pragma unroll
    for (int r = 0; r < GR; r++) a[r] = 0.f;
    const float4* W4 = (const float4*)(gcn_W + (size_t)d * DM + half * D);
    for (int f4 = 0; f4 < D / 4; ++f4) {
        float4 w = W4[f4];
        #pragma unroll
        for (int r = 0; r < GR; r++) {
            const float* c = &cs[r][half * D + f4 * 4];
            a[r] += w.x * c[0] + w.y * c[1] + w.z * c[2] + w.w * c[3];
        }
    }
    #pragma unroll
    for (int r = 0; r < GR; r++) pp[r][tid] = a[r];
    __syncthreads();
    if (tid < D) {
        #pragma unroll
        for (int r = 0; r < GR; r++) {
            float h = pp[r][tid] + pp[r][tid + D] + gcn_wb[tid] + gcn_b[tid];
            float th = tanh_fast(h);
            out[(size_t)(m0 + r) * D + tid] = th;
            out_bf[(size_t)(m0 + r) * D + tid] = f2bf(th);
        }
    }
}

// ---------------- 64x128-tile bf16 MFMA GEMM (2 blocks/CU for latency overlap) ----------------
#define GEMM64_VARS()                                                         \
    __shared__ __align__(16) ushort As[64][LDP];                              \
    __shared__ __align__(16) ushort Bs[128][LDP];                             \
    int tid = threadIdx.x;                                                    \
    int wave = tid >> 6, lane = tid & 63;                                     \
    int quad = lane >> 4, l16 = lane & 15;                                    \
    int wm = (wave >> 1) * 32, wn = (wave & 1) * 64;

#define GEMM64_CORE(AP, BP, KDIM)                                             \
    floatx4 acc[2][4];                                                        \
    _Pragma("unroll")                                                         \
    for (int i = 0; i < 2; i++)                                               \
        _Pragma("unroll")                                                     \
        for (int j = 0; j < 4; j++) acc[i][j] = (floatx4){0.f, 0.f, 0.f, 0.f};\
    for (int k0 = 0; k0 < (KDIM); k0 += BKT) {                                \
        __syncthreads();                                                      \
        _Pragma("unroll")                                                     \
        for (int t = 0; t < 2; t++) {                                         \
            int ch = t * 256 + tid;                                           \
            int r = ch >> 3, c8 = (ch & 7) * 8;                               \
            *(uint4*)&As[r][c8] = *(const uint4*)&(AP)[(size_t)(bm * 64 + r) * (KDIM) + k0 + c8]; \
        }                                                                     \
        _Pragma("unroll")                                                     \
        for (int t = 0; t < 4; t++) {                                         \
            int ch = t * 256 + tid;                                           \
            int r = ch >> 3, c8 = (ch & 7) * 8;                               \
            *(uint4*)&Bs[r][c8] = *(const uint4*)&(BP)[(size_t)(bn * 128 + r) * (KDIM) + k0 + c8]; \
        }                                                                     \
        __syncthreads();                                                      \
        _Pragma("unroll")                                                     \
        for (int kk = 0; kk < BKT; kk += 32) {                                \
            bf16x8 af[2], bv[4];                                              \
            _Pragma("unroll")                                                 \
            for (int i = 0; i < 2; i++)                                       \
                af[i] = *(const bf16x8*)&As[wm + i * 16 + l16][kk + quad * 8];\
            _Pragma("unroll")                                                 \
            for (int j = 0; j < 4; j++)                                       \
                bv[j] = *(const bf16x8*)&Bs[wn + j * 16 + l16][kk + quad * 8];\
            _Pragma("unroll")                                                 \
            for (int i = 0; i < 2; i++)                                       \
                _Pragma("unroll")                                             \
                for (int j = 0; j < 4; j++)                                   \
                    acc[i][j] = __builtin_amdgcn_mfma_f32_16x16x32_bf16(      \
                        af[i], bv[j], acc[i][j], 0, 0, 0);                    \
        }                                                                     \
    }

// se GEMM1: t1 = relu(x @ w1^T + b1), bf16 out.  grid (66, 4)
__global__ __launch_bounds__(256) void se_gemm1_kernel(
    const ushort* __restrict__ A, const ushort* __restrict__ B,
    const float* __restrict__ b1, ushort* __restrict__ Cbf)
{
    GEMM64_VARS();
    int bm = blockIdx.x, bn = blockIdx.y;
    GEMM64_CORE(A, B, DM);
    #pragma unroll
    for (int i = 0; i < 2; i++) {
        #pragma unroll
        for (int j = 0; j < 4; j++) {
            int row = bm * 64 + wm + i * 16 + quad * 4;
            int col = bn * 128 + wn + j * 16 + l16;
            float bb = b1[col];
            #pragma unroll
            for (int rr = 0; rr < 4; rr++)
                Cbf[(size_t)(row + rr) * DI + col] = f2bf(fmaxf(acc[i][j][rr] + bb, 0.f));
        }
    }
}

// se GEMM2: y = t1 @ w2^T + b2 + x, fp32 out.  grid (66, 2)
__global__ __launch_bounds__(256) void se_gemm2_kernel(
    const ushort* __restrict__ A, const ushort* __restrict__ B,
    const float* __restrict__ b2, const float* __restrict__ xres,
    float* __restrict__ C)
{
    GEMM64_VARS();
    int bm = blockIdx.x, bn = blockIdx.y;
    GEMM64_CORE(A, B, DI);
    #pragma unroll
    for (int i = 0; i < 2; i++) {
        #pragma unroll
        for (int j = 0; j < 4; j++) {
            int row = bm * 64 + wm + i * 16 + quad * 4;
            int col = bn * 128 + wn + j * 16 + l16;
            float bb = b2[col];
            #pragma unroll
            for (int rr = 0; rr < 4; rr++)
                C[(size_t)(row + rr) * DM + col] =
                    acc[i][j][rr] + bb + xres[(size_t)(row + rr) * DM + col];
        }
    }
}

// ---------------- LayerNorm ----------------
#define LN_ROWS 8
__global__ __launch_bounds__(256) void ln_kernel(
    const float* __restrict__ ys, const float* __restrict__ g,
    const float* __restrict__ b, float* __restrict__ outf,
    ushort* __restrict__ outbf)
{
    int tid = threadIdx.x;
    int wave = tid >> 6, lane = tid & 63;
    int r0 = blockIdx.x * LN_ROWS;
    for (int rr = 0; rr < 2; ++rr) {
        int r = r0 + wave * 2 + rr;
        float vals[4];
        float s = 0.f;
        #pragma unroll
        for (int e = 0; e < 4; e++) {
            vals[e] = ys[(size_t)r * DM + e * 64 + lane];
            s += vals[e];
        }
        #pragma unroll
        for (int off = 32; off; off >>= 1) s += __shfl_xor(s, off);
        float mu = s * (1.f / DM);
        float v = 0.f;
        #pragma unroll
        for (int e = 0; e < 4; e++) { float dd = vals[e] - mu; v += dd * dd; }
        #pragma unroll
        for (int off = 32; off; off >>= 1) v += __shfl_xor(v, off);
        float rstd = rsqrtf(v * (1.f / DM) + 1e-5f);
        #pragma unroll
        for (int e = 0; e < 4; e++) {
            int dd = e * 64 + lane;
            float ov = (vals[e] - mu) * rstd * g[dd] + b[dd];
            outf[(size_t)r * DM + dd] = ov;
            outbf[(size_t)r * DM + dd] = f2bf(ov);
        }
    }
}

// ---------------- LSTM GEMM step 1 + fused sgw (blocks 512..515) ----------------
// 1D grid of 516 blocks: [0,512) gemm0 (bm=bid>>3 in [0,64), bn=bid&7);
// [512,516) sgw. B = wcomb cols [0,256) (wih half, row stride 512).
// No P0f: steps 2-4 recompute wih@ln inside a combined K=512 chain instead of
// reading 16 MB of cached partials (r11 change — saves ~56 MB of traffic).
// Cf layout: [tile2=bm*8+bn][i][tid][rr]
__global__ __launch_bounds__(256) void lstm_gemm0_sgw_kernel(
    const ushort* __restrict__ A, const ushort* __restrict__ wcomb,
    const float* __restrict__ bsumP, const float* __restrict__ lnf,
    float* __restrict__ Cf, ushort* __restrict__ h_out,
    const float* __restrict__ W_hh, const float* __restrict__ b_ih,
    const float* __restrict__ b_hh, float* __restrict__ sg,
    float* __restrict__ gaddP)
{
    if (blockIdx.x >= 512) {
        // ---- sgw section ----
        __shared__ float s[DM];
        int tid = threadIdx.x;
        int sb = blockIdx.x - 512;
        float a = 0.f;
        for (int r = 0; r < BS; r++) a += lnf[(size_t)(BQ + r) * DM + tid];
        a *= (1.f / BS);
        s[tid] = a;
        if (sb == 0) sg[tid] = a;
        __syncthreads();

        int idx = sb * 256 + tid;              // 0..1023
        int g = idx >> 8, u = idx & 255;       // gate, live unit
        int oldrow = g * 512 + u;
        const float4* w4 = (const float4*)(W_hh + (size_t)oldrow * HH + DM);
        float acc = 0.f;
        for (int f4 = 0; f4 < DM / 4; ++f4) {
            float4 w = w4[f4];
            acc += w.x * s[f4 * 4] + w.y * s[f4 * 4 + 1] + w.z * s[f4 * 4 + 2] + w.w * s[f4 * 4 + 3];
        }
        float bs = b_ih[oldrow] + b_hh[oldrow];
        int n = (u >> 5) * 128 + ((u >> 4) & 1) * 64 + g * 16 + (u & 15);
        gaddP[n] = bs + acc;
        return;
    }

    // ---- gemm0 section: K=256 over wih half of wcomb (same math as before) ----
    GEMM64_VARS();
    int bm = blockIdx.x >> 3, bn = blockIdx.x & 7;
    floatx4 acc[2][4];
    #pragma unroll
    for (int i = 0; i < 2; i++)
        #pragma unroll
        for (int j = 0; j < 4; j++) acc[i][j] = (floatx4){0.f, 0.f, 0.f, 0.f};
    for (int k0 = 0; k0 < GK; k0 += BKT) {
        __syncthreads();
        #pragma unroll
        for (int t = 0; t < 2; t++) {
            int ch = t * 256 + tid;
            int r = ch >> 3, c8 = (ch & 7) * 8;
            *(uint4*)&As[r][c8] = *(const uint4*)&A[(size_t)(bm * 64 + r) * GK + k0 + c8];
        }
        #pragma unroll
        for (int t = 0; t < 4; t++) {
            int ch = t * 256 + tid;
            int r = ch >> 3, c8 = (ch & 7) * 8;
            *(uint4*)&Bs[r][c8] = *(const uint4*)&wcomb[(size_t)(bn * 128 + r) * 512 + k0 + c8];
        }
        __syncthreads();
        #pragma unroll
        for (int kk = 0; kk < BKT; kk += 32) {
            bf16x8 af[2], bv[4];
            #pragma unroll
            for (int i = 0; i < 2; i++)
                af[i] = *(const bf16x8*)&As[wm + i * 16 + l16][kk + quad * 8];
            #pragma unroll
            for (int j = 0; j < 4; j++)
                bv[j] = *(const bf16x8*)&Bs[wn + j * 16 + l16][kk + quad * 8];
            #pragma unroll
            for (int i = 0; i < 2; i++)
                #pragma unroll
                for (int j = 0; j < 4; j++)
                    acc[i][j] = __builtin_amdgcn_mfma_f32_16x16x32_bf16(
                        af[i], bv[j], acc[i][j], 0, 0, 0);
        }
    }
    int u = bn * 32 + (wn ? 16 : 0) + l16;
    size_t tile = (size_t)bm * 8 + bn;
    float b4[4];
    #pragma unroll
    for (int j = 0; j < 4; j++) b4[j] = bsumP[bn * 128 + wn + j * 16 + l16];
    #pragma unroll
    for (int i = 0; i < 2; i++) {
        int row = bm * 64 + wm + i * 16 + quad * 4;
        floatx4 cv4;
        #pragma unroll
        for (int rr = 0; rr < 4; rr++) {
            float iv = acc[i][0][rr] + b4[0];
            float gv = acc[i][2][rr] + b4[2];
            float ov = acc[i][3][rr] + b4[3];
            float cv = sigmoidf_(iv) * tanh_fast(gv);
            cv4[rr] = cv;
            float h = lnf[(size_t)(row + rr) * DM + u] + sigmoidf_(ov) * tanh_fast(cv);
            h_out[(size_t)(row + rr) * DM + u] = f2bf(h);
        }
        *(floatx4*)&Cf[((tile * 2 + i) * 256 + tid) * 4] = cv4;
    }
}

// ---------------- LSTM steps 2..4: combined K=512 chain [ln | h] @ wcomb^T ----------------
// grid (64, 8). A sources: lnbf (k<256) then hin (k>=256); B = wcomb (stride 512).
// gates = acc + gaddP (gaddP = biases + whh_r@sg). No P0f read.
__global__ __launch_bounds__(256) void lstm_step_kernel(
    const ushort* __restrict__ lnbf, const ushort* __restrict__ hin,
    const ushort* __restrict__ wcomb, const float* __restrict__ gaddP,
    const float* __restrict__ lnf, float* __restrict__ Cf,
    ushort* __restrict__ h_out, float* __restrict__ hf_out, int last)
{
    GEMM64_VARS();
    int bm = blockIdx.x, bn = blockIdx.y;
    floatx4 acc[2][4];
    #pragma unroll
    for (int i = 0; i < 2; i++)
        #pragma unroll
        for (int j = 0; j < 4; j++) acc[i][j] = (floatx4){0.f, 0.f, 0.f, 0.f};
    for (int k0 = 0; k0 < 512; k0 += BKT) {
        const ushort* Abase = (k0 < 256) ? (lnbf + k0) : (hin + (k0 - 256));
        __syncthreads();
        #pragma unroll
        for (int t = 0; t < 2; t++) {
            int ch = t * 256 + tid;
            int r = ch >> 3, c8 = (ch & 7) * 8;
            *(uint4*)&As[r][c8] = *(const uint4*)&Abase[(size_t)(bm * 64 + r) * 256 + c8];
        }
        #pragma unroll
        for (int t = 0; t < 4; t++) {
            int ch = t * 256 + tid;
            int r = ch >> 3, c8 = (ch & 7) * 8;
            *(uint4*)&Bs[r][c8] = *(const uint4*)&wcomb[(size_t)(bn * 128 + r) * 512 + k0 + c8];
        }
        __syncthreads();
        #pragma unroll
        for (int kk = 0; kk < BKT; kk += 32) {
            bf16x8 af[2], bv[4];
            #pragma unroll
            for (int i = 0; i < 2; i++)
                af[i] = *(const bf16x8*)&As[wm + i * 16 + l16][kk + quad * 8];
            #pragma unroll
            for (int j = 0; j < 4; j++)
                bv[j] = *(const bf16x8*)&Bs[wn + j * 16 + l16][kk + quad * 8];
            #pragma unroll
            for (int i = 0; i < 2; i++)
                #pragma unroll
                for (int j = 0; j < 4; j++)
                    acc[i][j] = __builtin_amdgcn_mfma_f32_16x16x32_bf16(
                        af[i], bv[j], acc[i][j], 0, 0, 0);
        }
    }
    int u = bn * 32 + (wn ? 16 : 0) + l16;
    size_t tile = (size_t)bm * 8 + bn;
    float g4[4];
    #pragma unroll
    for (int j = 0; j < 4; j++) g4[j] = gaddP[bn * 128 + wn + j * 16 + l16];
    #pragma unroll
    for (int i = 0; i < 2; i++) {
        int row = bm * 64 + wm + i * 16 + quad * 4;
        floatx4 cprev = *(const floatx4*)&Cf[((tile * 2 + i) * 256 + tid) * 4];
        floatx4 cnew;
        #pragma unroll
        for (int rr = 0; rr < 4; rr++) {
            float iv = acc[i][0][rr] + g4[0];
            float fv = acc[i][1][rr] + g4[1];
            float gv = acc[i][2][rr] + g4[2];
            float ov = acc[i][3][rr] + g4[3];
            float cv = sigmoidf_(fv) * cprev[rr] + sigmoidf_(iv) * tanh_fast(gv);
            cnew[rr] = cv;
            float h = lnf[(size_t)(row + rr) * DM + u] + sigmoidf_(ov) * tanh_fast(cv);
            if (last) hf_out[(size_t)(row + rr) * DM + u] = h;
            else      h_out[(size_t)(row + rr) * DM + u] = f2bf(h);
        }
        *(floatx4*)&Cf[((tile * 2 + i) * 256 + tid) * 4] = cnew;
    }
}

// ---------------- final cosine ----------------
__global__ __launch_bounds__(256) void final_kernel(
    const float* __restrict__ h_ws, const float* __restrict__ sg,
    float* __restrict__ outp)
{
    __shared__ float sgs[DM];
    int tid = threadIdx.x;
    sgs[tid] = sg[tid];
    __syncthreads();
    int wave = tid >> 6, lane = tid & 63;
    float sn = 0.f;
    #pragma unroll
    for (int e = 0; e < 4; e++) { float v = sgs[e * 64 + lane]; sn += v * v; }
    #pragma unroll
    for (int off = 32; off; off >>= 1) sn += __shfl_xor(sn, off);
    float sgnorm = fmaxf(sqrtf(sn), 1e-12f);

    int row = blockIdx.x * 4 + wave;
    const float* h = h_ws + (size_t)row * DM;
    float dot = 0.f, hn = 0.f;
    #pragma unroll
    for (int e = 0; e < 4; e++) {
        float hv = h[e * 64 + lane];
        dot += hv * sgs[e * 64 + lane];
        hn += hv * hv;
    }
    #pragma unroll
    for (int off = 32; off; off >>= 1) { dot += __shfl_xor(dot, off); hn += __shfl_xor(hn, off); }
    if (lane == 0) outp[row] = dot / (fmaxf(sqrtf(hn), 1e-12f) * sgnorm);
}

extern "C" void kernel_launch(void* const* d_in, const int* in_sizes, int n_in,
                              void* d_out, int out_size, void* d_ws, size_t ws_size,
                              hipStream_t stream)
{
    const int* query    = (const int*)d_in[0];
    const int* support  = (const int*)d_in[1];
    const int* q_l_conn = (const int*)d_in[2];
    const int* q_r_conn = (const int*)d_in[4];
    const int* s_l_conn = (const int*)d_in[6];
    const int* s_r_conn = (const int*)d_in[8];
    const float* emb    = (const float*)d_in[10];
    const float* gcn_W  = (const float*)d_in[11];
    const float* gcn_wb = (const float*)d_in[12];
    const float* gcn_b  = (const float*)d_in[13];
    const float* se_w1  = (const float*)d_in[14];
    const float* se_b1  = (const float*)d_in[15];
    const float* se_w2  = (const float*)d_in[16];
    const float* se_b2  = (const float*)d_in[17];
    const float* ln_g   = (const float*)d_in[18];
    const float* ln_b   = (const float*)d_in[19];
    const float* W_ih   = (const float*)d_in[20];
    const float* W_hh   = (const float*)d_in[21];
    const float* b_ih   = (const float*)d_in[22];
    const float* b_hh   = (const float*)d_in[23];
    float* out = (float*)d_out;

    char* wsb = (char*)d_ws;
    float*  xf     = (float*)wsb;  wsb += (size_t)BM2 * DM * 4;   // gcn fp32 out
    ushort* xb     = (ushort*)wsb; wsb += (size_t)BM2 * DM * 2;   // gcn bf16 out
    ushort* t1_bf  = (ushort*)wsb; wsb += (size_t)BM2 * DI * 2;   // relu(ffn1)
    float*  ys     = (float*)wsb;  wsb += (size_t)BM2 * DM * 4;   // pre-LN
    float*  ln_f   = (float*)wsb;  wsb += (size_t)BM2 * DM * 4;   // post-LN fp32
    ushort* ln_bf  = (ushort*)wsb; wsb += (size_t)BM2 * DM * 2;   // post-LN bf16
    float*  sg     = (float*)wsb;  wsb += DM * 4;
    float*  bsumP  = (float*)wsb;  wsb += G2 * 4;
    float*  gaddP  = (float*)wsb;  wsb += G2 * 4;
    ushort* wcomb  = (ushort*)wsb; wsb += (size_t)G2 * 512 * 2;   // [wih|whh] permuted
    ushort* w1_bf  = (ushort*)wsb; wsb += (size_t)DI * DM * 2;
    ushort* w2_bf  = (ushort*)wsb; wsb += (size_t)DM * DI * 2;
    float*  catm   = (float*)wsb;  wsb += (size_t)NEB * DM * 4;   // 8448 x 256
    float*  Cf     = (float*)wsb;  wsb += (size_t)BQ * DM * 4;    // live c only
    ushort* h_bfA  = (ushort*)wsb; wsb += (size_t)BQ * DM * 2;
    ushort* h_bfB  = (ushort*)wsb; wsb += (size_t)BQ * DM * 2;
    float*  h_f    = (float*)wsb;  wsb += (size_t)BQ * DM * 4;

    ne_prep_kernel<<<NEB + G2 + 512, 256, 0, stream>>>(
        q_l_conn, q_r_conn, query, s_l_conn, s_r_conn, support,
        emb, catm,
        W_ih, W_hh, b_ih, b_hh, se_w1, se_w2,
        wcomb, bsumP, w1_bf, w2_bf);
    gcn_kernel<<<(BM2 * 2) / GR, 256, 0, stream>>>(catm, gcn_W, gcn_wb, gcn_b,
                                                   xf, xb);
    { dim3 g1(BM2 / 64, DI / 128);    // (66, 4)
      se_gemm1_kernel<<<g1, 256, 0, stream>>>(xb, w1_bf, se_b1, t1_bf); }
    { dim3 g2(BM2 / 64, DM / 128);    // (66, 2)
      se_gemm2_kernel<<<g2, 256, 0, stream>>>(t1_bf, w2_bf, se_b2, xf, ys); }
    ln_kernel<<<BM2 / LN_ROWS, 256, 0, stream>>>(ys, ln_g, ln_b, ln_f, ln_bf);

    lstm_gemm0_sgw_kernel<<<516, 256, 0, stream>>>(
        ln_bf, wcomb, bsumP, ln_f, Cf, h_bfA,
        W_hh, b_ih, b_hh, sg, gaddP);

    dim3 ggrid(BQ / 64, G2 / 128);    // (64, 8)
    lstm_step_kernel<<<ggrid, 256, 0, stream>>>(ln_bf, h_bfA, wcomb, gaddP, ln_f,
                                                Cf, h_bfB, h_f, 0);
    lstm_step_kernel<<<ggrid, 256, 0, stream>>>(ln_bf, h_bfB, wcomb, gaddP, ln_f,
                                                Cf, h_bfA, h_f, 0);
    lstm_step_kernel<<<ggrid, 256, 0, stream>>>(ln_bf, h_bfA, wcomb, gaddP, ln_f,
                                                Cf, h_bfB, h_f, 1);
    final_kernel<<<BQ / 4, 256, 0, stream>>>(h_f, sg, out);
}